// Round 2
// baseline (246.849 us; speedup 1.0000x reference)
//
#include <hip/hip_runtime.h>

#define BATCH_L 524288
#define NL 40
#define NXL 20
#define BLOCK 256
#define GRID 2048
#define NTHREADS (GRID * BLOCK)              // 524288
#define NCHUNK (BATCH_L * 10)                // 5,242,880 float4 chunks per array
#define CITERS (NCHUNK / NTHREADS)           // 10 chunks per thread
#define STAGES 5                             // loads in flight per group
#define GROUPS (CITERS / STAGES)             // 2

// R6: explicit 5-deep load pipeline. R5 proved the 2.7 TB/s plateau is not a
// coalescing problem (perfect dwordx4 == 80B-stride). Model: read BW =
// lines_in_flight * 128B / miss_latency; VGPR=20 meant only ~4 loads in
// flight per wave -> MLP-starved. Here all 25 loads of a 5-chunk group issue
// before any compute (first consume waits at vmcnt(20), keeping 20 loads
// outstanding through the compute phase). VGPR ~90 -> 16 waves/CU, but
// per-CU outstanding wave-loads ~400 vs ~160. Math + accumulation order are
// bit-identical to R5 (absmax 0 preserved).
__global__ void hybrid_loss_main(
    const float4* __restrict__ pred4,
    const float4* __restrict__ targ4,
    const float4* __restrict__ ycur4,
    double* __restrict__ partials)     // [GRID][2]
{
    const int t = blockIdx.x * BLOCK + threadIdx.x;
    const float*  __restrict__ predf = reinterpret_cast<const float*>(pred4);
    const float2* __restrict__ pred2 = reinterpret_cast<const float2*>(pred4);

    double sdd = 0.0, spi = 0.0;

    for (int g = 0; g < GROUPS; ++g) {
        float4 P[STAGES], T[STAGES], Y[STAGES];
        float2 M[STAGES];
        float  R[STAGES];
        int    CR[STAGES];

        // ---- load phase: issue all 25 loads, no consumes ----
#pragma unroll
        for (int s = 0; s < STAGES; ++s) {
            const unsigned chunk =
                (unsigned)t + (unsigned)(g * STAGES + s) * (unsigned)NTHREADS;
            const unsigned row   = chunk / 10u;          // magic-mul
            const int      cr    = (int)(chunk - row * 10u);
            const int      c4    = cr * 4;
            const unsigned rbase = row * (unsigned)NL;

            const int im2 = (cr == 0) ? 38 : (c4 - 2);   // {p[q-2], p[q-1]} (f2-aligned)
            const int ip1 = (cr == 9) ? 0  : (c4 + 4);   // p[q+4]

            P[s] = pred4[chunk];
            T[s] = targ4[chunk];
            Y[s] = ycur4[chunk];
            M[s] = pred2[(rbase + (unsigned)im2) >> 1];
            R[s] = predf[rbase + (unsigned)ip1];
            CR[s] = cr;
        }

        // ---- compute phase: consume in issue order ----
#pragma unroll
        for (int s = 0; s < STAGES; ++s) {
            const float4 P_ = P[s], T_ = T[s], Y_ = Y[s];
            const float2 M_ = M[s];
            const float  R_ = R[s];

            // Data-driven MSE: chunk cols all < 20 iff cr < 5.
            {
                const float d0 = P_.x - T_.x, d1 = P_.y - T_.y;
                const float d2 = P_.z - T_.z, d3 = P_.w - T_.w;
                const float sacc = d0 * d0 + d1 * d1 + d2 * d2 + d3 * d3;
                if (CR[s] < 5) sdd += (double)sacc;
            }
            // Physics: d_i = (101 p_i - 100 y_i - 8) - (p_{i+1} - p_{i-2}) * p_{i-1}
            {
                const float d0 = (101.f * P_.x - 100.f * Y_.x - 8.f) - (P_.y - M_.x) * M_.y;
                const float d1 = (101.f * P_.y - 100.f * Y_.y - 8.f) - (P_.z - M_.y) * P_.x;
                const float d2 = (101.f * P_.z - 100.f * Y_.z - 8.f) - (P_.w - P_.x) * P_.y;
                const float d3 = (101.f * P_.w - 100.f * Y_.w - 8.f) - (R_   - P_.y) * P_.z;
                spi += (double)(d0 * d0 + d1 * d1 + d2 * d2 + d3 * d3);
            }
        }
    }

    // Wave shuffle reduction in double -> LDS -> per-block partial.
#pragma unroll
    for (int off = 32; off > 0; off >>= 1) {
        sdd += __shfl_down(sdd, off, 64);
        spi += __shfl_down(spi, off, 64);
    }
    __shared__ double lds_red[2 * (BLOCK / 64)];
    const int lane = threadIdx.x & 63;
    const int wave = threadIdx.x >> 6;
    if (lane == 0) { lds_red[2 * wave] = sdd; lds_red[2 * wave + 1] = spi; }
    __syncthreads();
    if (threadIdx.x == 0) {
        double tsd = 0.0, tsp = 0.0;
#pragma unroll
        for (int w = 0; w < BLOCK / 64; ++w) {
            tsd += lds_red[2 * w];
            tsp += lds_red[2 * w + 1];
        }
        partials[2 * blockIdx.x]     = tsd;   // every slot written every launch
        partials[2 * blockIdx.x + 1] = tsp;
    }
}

__global__ __launch_bounds__(256) void hybrid_loss_finalize(
    const double* __restrict__ partials, float* __restrict__ out)
{
    const double2* __restrict__ p2 = reinterpret_cast<const double2*>(partials);
    double sd = 0.0, sp = 0.0;
    for (int m = threadIdx.x; m < GRID; m += 256) {
        const double2 v = p2[m];
        sd += v.x; sp += v.y;
    }
#pragma unroll
    for (int off = 32; off > 0; off >>= 1) {
        sd += __shfl_down(sd, off, 64);
        sp += __shfl_down(sp, off, 64);
    }
    __shared__ double lds[8];
    const int lane = threadIdx.x & 63;
    const int wave = threadIdx.x >> 6;
    if (lane == 0) { lds[2 * wave] = sd; lds[2 * wave + 1] = sp; }
    __syncthreads();
    if (threadIdx.x == 0) {
        double tsd = 0.0, tsp = 0.0;
#pragma unroll
        for (int w = 0; w < 4; ++w) { tsd += lds[2 * w]; tsp += lds[2 * w + 1]; }
        const double l_dd = tsd / ((double)BATCH_L * NXL);
        const double l_pi = tsp / ((double)BATCH_L * NL);
        out[0] = (float)(l_dd + 0.1 * l_pi);
        out[1] = (float)l_dd;
        out[2] = (float)l_pi;
    }
}

extern "C" void kernel_launch(void* const* d_in, const int* in_sizes, int n_in,
                              void* d_out, int out_size, void* d_ws, size_t ws_size,
                              hipStream_t stream) {
    const float4* pred = (const float4*)d_in[0];
    const float4* targ = (const float4*)d_in[1];
    const float4* ycur = (const float4*)d_in[2];
    double* partials = (double*)d_ws;          // GRID * 2 doubles = 32 KB
    float* out = (float*)d_out;

    hybrid_loss_main<<<GRID, BLOCK, 0, stream>>>(pred, targ, ycur, partials);
    hybrid_loss_finalize<<<1, 256, 0, stream>>>(partials, out);
}

// Round 3
// 242.157 us; speedup vs baseline: 1.0194x; 1.0194x over previous
//
#include <hip/hip_runtime.h>

#define BATCH_L 524288
#define NL 40
#define NXL 20
#define BLOCK 256
#define GRID 5120                            // 20 blocks/CU: oversubscribed, backfills
#define NTHREADS (GRID * BLOCK)              // 1,310,720
#define NCHUNK (BATCH_L * 10)                // 5,242,880 float4 chunks per array
#define CITERS (NCHUNK / NTHREADS)           // 4 chunks per thread
#define STAGES 2                             // loads in flight per group (fits 64 VGPR)
#define GROUPS (CITERS / STAGES)             // 2

// R7: occupancy/backfill fix. R6's deep pipeline SPILLED (VGPR=64 cap chosen by
// the compiler heuristic, WRITE_SIZE=28.7MB of scratch) so the MLP test was
// confounded. Real counters show: HBM 1.7 TB/s (21%), VALUBusy 7.5%,
// OccupancyPercent 39% -> latency-bound with too few resident waves. The old
// exact-fit grid (8 blocks/CU, zero backfill) drains for much of the kernel.
// This version: 2.5x oversubscribed grid (20 blocks/CU), 4 chunks/thread in
// 2 explicit 2-deep groups (~30 VGPRs of staged data, total ~55 -> stays in
// the <=64-VGPR / 8-waves-per-SIMD tier, NO spills). Math + accumulation in
// double is unchanged (f64 accum error << f32 ulp -> bit-equal outputs).
__global__ void hybrid_loss_main(
    const float4* __restrict__ pred4,
    const float4* __restrict__ targ4,
    const float4* __restrict__ ycur4,
    double* __restrict__ partials)     // [GRID][2]
{
    const int t = blockIdx.x * BLOCK + threadIdx.x;
    const float*  __restrict__ predf = reinterpret_cast<const float*>(pred4);
    const float2* __restrict__ pred2 = reinterpret_cast<const float2*>(pred4);

    double sdd = 0.0, spi = 0.0;

#pragma unroll
    for (int g = 0; g < GROUPS; ++g) {
        float4 P[STAGES], T[STAGES], Y[STAGES];
        float2 M[STAGES];
        float  R[STAGES];
        int    CR[STAGES];

        // ---- load phase: issue all 10 loads of this group, no consumes ----
#pragma unroll
        for (int s = 0; s < STAGES; ++s) {
            const unsigned chunk =
                (unsigned)t + (unsigned)(g * STAGES + s) * (unsigned)NTHREADS;
            const unsigned row   = chunk / 10u;          // magic-mul
            const int      cr    = (int)(chunk - row * 10u);
            const int      c4    = cr * 4;
            const unsigned rbase = row * (unsigned)NL;

            const int im2 = (cr == 0) ? 38 : (c4 - 2);   // {p[q-2], p[q-1]} (f2-aligned)
            const int ip1 = (cr == 9) ? 0  : (c4 + 4);   // p[q+4]

            P[s] = pred4[chunk];
            T[s] = targ4[chunk];
            Y[s] = ycur4[chunk];
            M[s] = pred2[(rbase + (unsigned)im2) >> 1];
            R[s] = predf[rbase + (unsigned)ip1];
            CR[s] = cr;
        }

        // ---- compute phase: consume in issue order ----
#pragma unroll
        for (int s = 0; s < STAGES; ++s) {
            const float4 P_ = P[s], T_ = T[s], Y_ = Y[s];
            const float2 M_ = M[s];
            const float  R_ = R[s];

            // Data-driven MSE: chunk cols all < 20 iff cr < 5.
            {
                const float d0 = P_.x - T_.x, d1 = P_.y - T_.y;
                const float d2 = P_.z - T_.z, d3 = P_.w - T_.w;
                const float sacc = d0 * d0 + d1 * d1 + d2 * d2 + d3 * d3;
                if (CR[s] < 5) sdd += (double)sacc;
            }
            // Physics: d_i = (101 p_i - 100 y_i - 8) - (p_{i+1} - p_{i-2}) * p_{i-1}
            {
                const float d0 = (101.f * P_.x - 100.f * Y_.x - 8.f) - (P_.y - M_.x) * M_.y;
                const float d1 = (101.f * P_.y - 100.f * Y_.y - 8.f) - (P_.z - M_.y) * P_.x;
                const float d2 = (101.f * P_.z - 100.f * Y_.z - 8.f) - (P_.w - P_.x) * P_.y;
                const float d3 = (101.f * P_.w - 100.f * Y_.w - 8.f) - (R_   - P_.y) * P_.z;
                spi += (double)(d0 * d0 + d1 * d1 + d2 * d2 + d3 * d3);
            }
        }
    }

    // Wave shuffle reduction in double -> LDS -> per-block partial.
#pragma unroll
    for (int off = 32; off > 0; off >>= 1) {
        sdd += __shfl_down(sdd, off, 64);
        spi += __shfl_down(spi, off, 64);
    }
    __shared__ double lds_red[2 * (BLOCK / 64)];
    const int lane = threadIdx.x & 63;
    const int wave = threadIdx.x >> 6;
    if (lane == 0) { lds_red[2 * wave] = sdd; lds_red[2 * wave + 1] = spi; }
    __syncthreads();
    if (threadIdx.x == 0) {
        double tsd = 0.0, tsp = 0.0;
#pragma unroll
        for (int w = 0; w < BLOCK / 64; ++w) {
            tsd += lds_red[2 * w];
            tsp += lds_red[2 * w + 1];
        }
        partials[2 * blockIdx.x]     = tsd;   // every slot written every launch
        partials[2 * blockIdx.x + 1] = tsp;
    }
}

__global__ __launch_bounds__(256) void hybrid_loss_finalize(
    const double* __restrict__ partials, float* __restrict__ out)
{
    const double2* __restrict__ p2 = reinterpret_cast<const double2*>(partials);
    double sd = 0.0, sp = 0.0;
    for (int m = threadIdx.x; m < GRID; m += 256) {
        const double2 v = p2[m];
        sd += v.x; sp += v.y;
    }
#pragma unroll
    for (int off = 32; off > 0; off >>= 1) {
        sd += __shfl_down(sd, off, 64);
        sp += __shfl_down(sp, off, 64);
    }
    __shared__ double lds[8];
    const int lane = threadIdx.x & 63;
    const int wave = threadIdx.x >> 6;
    if (lane == 0) { lds[2 * wave] = sd; lds[2 * wave + 1] = sp; }
    __syncthreads();
    if (threadIdx.x == 0) {
        double tsd = 0.0, tsp = 0.0;
#pragma unroll
        for (int w = 0; w < 4; ++w) { tsd += lds[2 * w]; tsp += lds[2 * w + 1]; }
        const double l_dd = tsd / ((double)BATCH_L * NXL);
        const double l_pi = tsp / ((double)BATCH_L * NL);
        out[0] = (float)(l_dd + 0.1 * l_pi);
        out[1] = (float)l_dd;
        out[2] = (float)l_pi;
    }
}

extern "C" void kernel_launch(void* const* d_in, const int* in_sizes, int n_in,
                              void* d_out, int out_size, void* d_ws, size_t ws_size,
                              hipStream_t stream) {
    const float4* pred = (const float4*)d_in[0];
    const float4* targ = (const float4*)d_in[1];
    const float4* ycur = (const float4*)d_in[2];
    double* partials = (double*)d_ws;          // GRID * 2 doubles = 80 KB
    float* out = (float*)d_out;

    hybrid_loss_main<<<GRID, BLOCK, 0, stream>>>(pred, targ, ycur, partials);
    hybrid_loss_finalize<<<1, 256, 0, stream>>>(partials, out);
}

// Round 4
// 238.364 us; speedup vs baseline: 1.0356x; 1.0159x over previous
//
#include <hip/hip_runtime.h>

#define BATCH_L 524288
#define NL 40
#define NXL 20
#define BLOCK 256
#define GRID 4096                      // NHALF/BLOCK: 1 half-row per thread, 16 blk/CU
#define NHALF (BATCH_L * 2)            // 1,048,576 half-rows == NTHREADS

// R8: force the MLP that R6 (spilled) and R7 (re-serialized to VGPR=32) never
// got. Structure = R0 half-rows (15 pure dwordx4 loads, zero halo loads, halo
// via shfl_xor with lane^1). Three fixes vs R0:
//   1. __launch_bounds__(256,4): 128-VGPR cap -> 60 VGPRs of staged loads fit
//      with NO spill (R3's (256,6)=85-reg cap was too tight) and the compiler
//      cannot re-serialize to chase 8 waves/SIMD.
//   2. ITERS=1 (grid 4096): all 15 loads issue once, 2x block oversubscription
//      for backfill.
//   3. sched_barrier(0) between loads and compute: scheduler may not sink
//      loads past consumes -> first consume waits at vmcnt(14), 15 in flight.
// Little's law: 16 waves/CU x 15 x 1KB = 245 KB in flight/CU vs the ~2.6
// loads/wave R7 achieved. Warm-L3 replays at identical 90us proved the cap is
// CU-side latency-serialization, not HBM/L3 bandwidth.
__global__ __launch_bounds__(BLOCK, 4) void hybrid_loss_main(
    const float4* __restrict__ pred4,
    const float4* __restrict__ targ4,
    const float4* __restrict__ ycur4,
    double* __restrict__ partials)     // [GRID][2]
{
    const int t = blockIdx.x * BLOCK + threadIdx.x;
    const float ddmask = (threadIdx.x & 1) ? 0.f : 1.f;  // h==0 half has the dd term
    const size_t c0 = (size_t)t * 5;                     // first float4 chunk

    // ---- issue all 15 independent, fully-coalesced dwordx4 loads ----
    float4 pc[5], tc[5], yc[5];
#pragma unroll
    for (int k = 0; k < 5; ++k) pc[k] = pred4[c0 + k];
#pragma unroll
    for (int k = 0; k < 5; ++k) tc[k] = targ4[c0 + k];
#pragma unroll
    for (int k = 0; k < 5; ++k) yc[k] = ycur4[c0 + k];
    __builtin_amdgcn_sched_barrier(0);   // nothing moves across: 15 loads stay issued

    float sdd = 0.f, spi = 0.f;

    float p[20];
#pragma unroll
    for (int k = 0; k < 5; ++k) {
        p[4 * k + 0] = pc[k].x; p[4 * k + 1] = pc[k].y;
        p[4 * k + 2] = pc[k].z; p[4 * k + 3] = pc[k].w;
    }

    // Data-driven MSE (masked: only the cols 0..19 half contributes).
    {
        float s = 0.f;
#pragma unroll
        for (int k = 0; k < 5; ++k) {
            const float d0 = pc[k].x - tc[k].x;
            const float d1 = pc[k].y - tc[k].y;
            const float d2 = pc[k].z - tc[k].z;
            const float d3 = pc[k].w - tc[k].w;
            s += d0 * d0 + d1 * d1 + d2 * d2 + d3 * d3;
        }
        sdd += ddmask * s;
    }

    // Boundary exchange with the partner half (lane t^1).
    const float prev2 = __shfl_xor(p[18], 1);
    const float prev1 = __shfl_xor(p[19], 1);
    const float nxt   = __shfl_xor(p[0], 1);

    // d_i = (101 p_i - 100 y_i - 8) - (p_{i+1} - p_{i-2}) * p_{i-1}
    {
        const float* y = reinterpret_cast<const float*>(yc);
        float d = (101.f * p[0] - 100.f * y[0] - 8.f) - (p[1] - prev2) * prev1;
        spi += d * d;
        d = (101.f * p[1] - 100.f * y[1] - 8.f) - (p[2] - prev1) * p[0];
        spi += d * d;
#pragma unroll
        for (int i = 2; i <= 18; ++i) {
            d = (101.f * p[i] - 100.f * y[i] - 8.f) - (p[i + 1] - p[i - 2]) * p[i - 1];
            spi += d * d;
        }
        d = (101.f * p[19] - 100.f * y[19] - 8.f) - (nxt - p[17]) * p[18];
        spi += d * d;
    }

    // Wave shuffle reduction in double -> LDS -> per-block partial.
    double sd = (double)sdd, sp = (double)spi;
#pragma unroll
    for (int off = 32; off > 0; off >>= 1) {
        sd += __shfl_down(sd, off, 64);
        sp += __shfl_down(sp, off, 64);
    }
    __shared__ double lds_red[2 * (BLOCK / 64)];
    const int lane = threadIdx.x & 63;
    const int wave = threadIdx.x >> 6;
    if (lane == 0) { lds_red[2 * wave] = sd; lds_red[2 * wave + 1] = sp; }
    __syncthreads();
    if (threadIdx.x == 0) {
        double tsd = 0.0, tsp = 0.0;
#pragma unroll
        for (int w = 0; w < BLOCK / 64; ++w) {
            tsd += lds_red[2 * w];
            tsp += lds_red[2 * w + 1];
        }
        partials[2 * blockIdx.x]     = tsd;   // every slot written every launch
        partials[2 * blockIdx.x + 1] = tsp;
    }
}

__global__ __launch_bounds__(256) void hybrid_loss_finalize(
    const double* __restrict__ partials, float* __restrict__ out)
{
    const double2* __restrict__ p2 = reinterpret_cast<const double2*>(partials);
    double sd = 0.0, sp = 0.0;
    for (int m = threadIdx.x; m < GRID; m += 256) {
        const double2 v = p2[m];
        sd += v.x; sp += v.y;
    }
#pragma unroll
    for (int off = 32; off > 0; off >>= 1) {
        sd += __shfl_down(sd, off, 64);
        sp += __shfl_down(sp, off, 64);
    }
    __shared__ double lds[8];
    const int lane = threadIdx.x & 63;
    const int wave = threadIdx.x >> 6;
    if (lane == 0) { lds[2 * wave] = sd; lds[2 * wave + 1] = sp; }
    __syncthreads();
    if (threadIdx.x == 0) {
        double tsd = 0.0, tsp = 0.0;
#pragma unroll
        for (int w = 0; w < 4; ++w) { tsd += lds[2 * w]; tsp += lds[2 * w + 1]; }
        const double l_dd = tsd / ((double)BATCH_L * NXL);
        const double l_pi = tsp / ((double)BATCH_L * NL);
        out[0] = (float)(l_dd + 0.1 * l_pi);
        out[1] = (float)l_dd;
        out[2] = (float)l_pi;
    }
}

extern "C" void kernel_launch(void* const* d_in, const int* in_sizes, int n_in,
                              void* d_out, int out_size, void* d_ws, size_t ws_size,
                              hipStream_t stream) {
    const float4* pred = (const float4*)d_in[0];
    const float4* targ = (const float4*)d_in[1];
    const float4* ycur = (const float4*)d_in[2];
    double* partials = (double*)d_ws;          // GRID * 2 doubles = 64 KB
    float* out = (float*)d_out;

    hybrid_loss_main<<<GRID, BLOCK, 0, stream>>>(pred, targ, ycur, partials);
    hybrid_loss_finalize<<<1, 256, 0, stream>>>(partials, out);
}